// Round 3
// baseline (420.059 us; speedup 1.0000x reference)
//
#include <hip/hip_runtime.h>
#include <math.h>

// Problem constants (fixed by reference setup_inputs)
#define B_ 16
#define C_ 512
#define N_ 4096   // 64*64
#define K_ 64

// Workspace layout (float offsets). Total ~689K floats = 2.76 MB.
#define OFF_PBIG    0         // [64 k][2048 dwords] bf16-pair packed param matrix (r = c*8+f)
#define OFF_INVSIG  131072    // [K][C] 1/sigma fp32
#define OFF_WSUM    163840    // [B][K]
#define OFF_GSUM    164864    // [B]
#define OFF_WX      164992    // [B][K][C] fp32 partial-1 (partial-0 aliases out0)

typedef short bf16x8 __attribute__((ext_vector_type(8)));   // 8 bf16 in 4 VGPRs
typedef float f32x16 __attribute__((ext_vector_type(16)));  // MFMA 32x32 accumulator

union U4 { uint4 u; bf16x8 b; };

__device__ __forceinline__ unsigned hi16(float f) { return __float_as_uint(f) >> 16; }
__device__ __forceinline__ unsigned hi16rne(float f) {
  return (__float_as_uint(f) + 0x8000u) >> 16;
}
__device__ __forceinline__ float fromhi(unsigned h) { return __uint_as_float(h << 16); }
// pack two floats' truncated-bf16 into one dword: low16 = bf16(lo), high16 = bf16(hi)
__device__ __forceinline__ unsigned pk(float lo, float hi) {
  return (__float_as_uint(lo) >> 16) | (__float_as_uint(hi) & 0xFFFF0000u);
}

// ---------------------------------------------------------------- kernel 1
// Build pbig, invsig; zero wsum/gsum. One block per k.
__global__ void k_prep(const float* __restrict__ anchor,
                       const float* __restrict__ sraw,
                       unsigned* __restrict__ pbig,
                       float* __restrict__ invsig,
                       float* __restrict__ wsum,
                       float* __restrict__ gsum) {
  const int k = blockIdx.x;
  const int t = threadIdx.x;
  __shared__ float s_is2[C_], s_m[C_];
  __shared__ float red[4];
  float part = 0.f;
#pragma unroll
  for (int r = 0; r < 2; r++) {
    int c = r * 256 + t;
    float a = anchor[k * C_ + c];
    float sg = 1.f / (1.f + __expf(-sraw[k * C_ + c]));
    float is = 1.f / sg;
    float is2 = is * is;
    s_is2[c] = is2;
    s_m[c] = -2.f * a * is2;
    invsig[k * C_ + c] = is;
    part = fmaf(a * a, is2, part);
  }
  float v = part;
#pragma unroll
  for (int off = 32; off; off >>= 1) v += __shfl_down(v, off);
  if ((t & 63) == 0) red[t >> 6] = v;
  __syncthreads();
  float cst = red[0] + red[1] + red[2] + red[3];
  unsigned ch = hi16(cst);
  unsigned clr = hi16rne(cst - fromhi(ch));
#pragma unroll
  for (int r = 0; r < 2; r++) {
    int c = r * 256 + t;
    float is2 = s_is2[c], m = s_m[c];
    unsigned ih = hi16(is2);
    unsigned ilr = hi16rne(is2 - fromhi(ih));
    unsigned mh = hi16(m);
    unsigned mlr = hi16rne(m - fromhi(mh));
    unsigned* p = pbig + (size_t)k * 2048 + c * 4;
    p[0] = ih | (ilr << 16);
    p[1] = ih | (mh << 16);
    p[2] = mlr | (mh << 16);
    p[3] = (c == 0) ? (ch | (clr << 16)) : 0u;
  }
  if (k == 0) {
    for (int i = t; i < B_ * K_; i += 256) wsum[i] = 0.f;
    if (t < B_) gsum[t] = 0.f;
  }
}

// ---------------------------------------------------------------- kernel 2
// MFMA distance GEMM (split-bf16, inner dim 4096) + in-register softmax.
// v3: same split-C structure as v2 (grid (N/128,B), 512 blocks, 2/CU) but
// ALL register-array indexing is compile-time static (v2's runtime-indexed
// acc[ktown] demoted the accumulators to scratch: +286 MB HBM writes).
// Wave-uniform branches on chalf select which statically-indexed half to
// exchange; merged result lives in statically-indexed own[2].
__global__ __launch_bounds__(256) void k_dist(
    const float* __restrict__ x,
    const unsigned* __restrict__ pbig,
    float* __restrict__ soft,
    float* __restrict__ wsum) {
  const int b = blockIdx.y;
  const int nblk = blockIdx.x * 128;
  const int tid = threadIdx.x;
  const int wid = tid >> 6;
  const int lane = tid & 63;
  const int l31 = lane & 31;
  const int lh = lane >> 5;
  const int chalf = wid & 1;                 // which C-half this wave sums
  const int ktown = chalf;                   // kt tile this wave owns post-exchange
  const int n0 = nblk + (wid >> 1) * 64;

  __shared__ unsigned ldsA[2 * 64 * 132];    // two chunk regions (67.6 KB)
  __shared__ float cred[4][2][32];           // per-wave per-ns per-column max
  __shared__ float csum[4][2][32];           // per-wave per-ns per-column expsum

  f32x16 acc[2][2];
#pragma unroll
  for (int kt = 0; kt < 2; kt++)
#pragma unroll
    for (int ns = 0; ns < 2; ns++)
#pragma unroll
      for (int i = 0; i < 16; i++) acc[kt][ns][i] = 0.f;

  const float* xb = x + (size_t)b * (C_ * N_);

  for (int t = 0; t < 8; t++) {
    // stage chunk t (region 0, c-half 0) and chunk t+8 (region 1, c-half 1)
    const uint4* src = (const uint4*)pbig;
#pragma unroll
    for (int it = 0; it < 16; it++) {
      int flat = tid + it * 256;             // 0..4095
      int region = flat >> 11;
      int within = flat & 2047;
      int k = within >> 5, q = within & 31;
      int ch = region * 8 + t;
      uint4 vv = src[(size_t)k * 512 + ch * 32 + q];
      *(uint4*)&ldsA[region * 8448 + k * 132 + q * 4] = vv;
    }
    __syncthreads();
    const unsigned* lbase = ldsA + chalf * 8448;
    const int cchunk = (chalf * 8 + t) * 32;
    for (int kstep = 0; kstep < 16; kstep++) {
      U4 a0, a1;
      a0.u = *(const uint4*)&lbase[l31 * 132 + kstep * 8 + lh * 4];
      a1.u = *(const uint4*)&lbase[(32 + l31) * 132 + kstep * 8 + lh * 4];
      const int c = cchunk + kstep * 2 + lh;
      const float* xr = xb + (size_t)c * N_;
#pragma unroll
      for (int ns = 0; ns < 2; ns++) {
        float xv = xr[n0 + ns * 32 + l31];
        float x2 = xv * xv;
        unsigned u = __float_as_uint(xv);
        unsigned u2 = __float_as_uint(x2);
        unsigned uhf = u & 0xFFFF0000u;
        unsigned u2hf = u2 & 0xFFFF0000u;
        float xl = xv - __uint_as_float(uhf);
        float x2l = x2 - __uint_as_float(u2hf);
        U4 bf;
        bf.u.x = (u2 >> 16) | u2hf;                                   // x2h | x2h
        bf.u.y = ((__float_as_uint(x2l) + 0x8000u) >> 16) | uhf;      // x2l | xh
        bf.u.z = (u >> 16) | ((__float_as_uint(xl) + 0x8000u) & 0xFFFF0000u); // xh | xl
        bf.u.w = (c == 0) ? 0x3F803F80u : 0u;                         // 1.0 | 1.0 @ c==0
        acc[0][ns] = __builtin_amdgcn_mfma_f32_32x32x16_bf16(a0.b, bf.b, acc[0][ns], 0, 0, 0);
        acc[1][ns] = __builtin_amdgcn_mfma_f32_32x32x16_bf16(a1.b, bf.b, acc[1][ns], 0, 0, 0);
      }
    }
    __syncthreads();
  }

  // ---- pairwise kt exchange (ALL STATIC register indices). Wave with
  // chalf==0 owns kt0: gives away acc[1], merges partner's kt0 into acc[0].
  float* exch = (float*)ldsA;                // [4][64][36] floats = 36.9 KB
  {
    float* pw = &exch[(wid * 64 + lane) * 36];
    if (chalf == 0) {
#pragma unroll
      for (int ns = 0; ns < 2; ns++)
#pragma unroll
        for (int q = 0; q < 4; q++)
          *(float4*)&pw[ns * 16 + q * 4] =
              make_float4(acc[1][ns][q * 4], acc[1][ns][q * 4 + 1],
                          acc[1][ns][q * 4 + 2], acc[1][ns][q * 4 + 3]);
    } else {
#pragma unroll
      for (int ns = 0; ns < 2; ns++)
#pragma unroll
        for (int q = 0; q < 4; q++)
          *(float4*)&pw[ns * 16 + q * 4] =
              make_float4(acc[0][ns][q * 4], acc[0][ns][q * 4 + 1],
                          acc[0][ns][q * 4 + 2], acc[0][ns][q * 4 + 3]);
    }
  }
  __syncthreads();
  f32x16 own[2];
  {
    const float* pex = &exch[((wid ^ 1) * 64 + lane) * 36];
    if (chalf == 0) {
#pragma unroll
      for (int ns = 0; ns < 2; ns++)
#pragma unroll
        for (int r = 0; r < 16; r++) own[ns][r] = acc[0][ns][r] + pex[ns * 16 + r];
    } else {
#pragma unroll
      for (int ns = 0; ns < 2; ns++)
#pragma unroll
        for (int r = 0; r < 16; r++) own[ns][r] = acc[1][ns][r] + pex[ns * 16 + r];
    }
  }

  // ---- cross-wave softmax over k=64 (k spans the wave pair) ----
  float* softb = soft + (size_t)b * (K_ * N_);
#pragma unroll
  for (int ns = 0; ns < 2; ns++) {
    float m = -3.4e38f;
#pragma unroll
    for (int r = 0; r < 16; r++) {
      float l = -0.5f * own[ns][r];
      own[ns][r] = l;
      m = fmaxf(m, l);
    }
    m = fmaxf(m, __shfl_xor(m, 32));
    if (lh == 0) cred[wid][ns][l31] = m;
  }
  __syncthreads();
#pragma unroll
  for (int ns = 0; ns < 2; ns++) {
    float m = fmaxf(cred[wid][ns][l31], cred[wid ^ 1][ns][l31]);
    float ss = 0.f;
#pragma unroll
    for (int r = 0; r < 16; r++) {
      float e = __expf(own[ns][r] - m);
      own[ns][r] = e;
      ss += e;
    }
    ss += __shfl_xor(ss, 32);
    if (lh == 0) csum[wid][ns][l31] = ss;
  }
  __syncthreads();
#pragma unroll
  for (int ns = 0; ns < 2; ns++) {
    float tot = csum[wid][ns][l31] + csum[wid ^ 1][ns][l31];
    float iv = 1.f / tot;
    const int nc = n0 + ns * 32 + l31;
#pragma unroll
    for (int r = 0; r < 16; r++) {
      float w = own[ns][r] * iv;
      own[ns][r] = w;
      int k = ktown * 32 + (r & 3) + 8 * (r >> 2) + 4 * lh;
      softb[(size_t)k * N_ + nc] = w;
    }
  }
  // ---- wsum: reduce own-kt rows over this pair's 64 n-columns ----
#pragma unroll
  for (int r = 0; r < 16; r++) {
    float v = own[0][r] + own[1][r];
    v += __shfl_xor(v, 1);
    v += __shfl_xor(v, 2);
    v += __shfl_xor(v, 4);
    v += __shfl_xor(v, 8);
    v += __shfl_xor(v, 16);
    if (l31 == 0) {
      int k = ktown * 32 + (r & 3) + 8 * (r >> 2) + 4 * lh;
      atomicAdd(&wsum[b * K_ + k], v);
    }
  }
}

// ---------------------------------------------------------------- kernel 3
// Aggregation GEMM via MFMA: wx[b,k,c] = sum_n soft[b,k,n]*x[b,c,n].
// grid (C/32, B, 2) -- n split in half across blockIdx.z, partials go to
// two buffers (z=0 aliases out0 region; z=1 in ws). 512 blocks -> 2/CU.
__global__ __launch_bounds__(256) void k_agg(const float* __restrict__ x,
                                             const float* __restrict__ soft,
                                             float* __restrict__ wxp0,
                                             float* __restrict__ wxp1) {
  const int ct = blockIdx.x;
  const int b = blockIdx.y;
  const int z = blockIdx.z;
  const int tid = threadIdx.x;
  const int wid = tid >> 6, lane = tid & 63, l31 = lane & 31, lh = lane >> 5;
  const int c0 = ct * 32;
  const int n0 = z * 2048 + wid * 512;
  __shared__ float red[4][64][36];  // stride 36 floats = 9x16B (odd) per lane

  f32x16 acc[2];
#pragma unroll
  for (int kt = 0; kt < 2; kt++)
#pragma unroll
    for (int i = 0; i < 16; i++) acc[kt][i] = 0.f;

  const float* sb = soft + (size_t)b * (K_ * N_);
  const float* xr = x + (size_t)b * (C_ * N_) + (size_t)(c0 + l31) * N_;
  const float* s0 = sb + (size_t)l31 * N_;
  const float* s1 = sb + (size_t)(32 + l31) * N_;

  for (int kstep = 0; kstep < 32; kstep++) {
    int nb = n0 + kstep * 16 + lh * 8;
    float4 f0 = *(const float4*)&s0[nb];
    float4 f1 = *(const float4*)&s0[nb + 4];
    float4 g0 = *(const float4*)&s1[nb];
    float4 g1 = *(const float4*)&s1[nb + 4];
    float4 h0 = *(const float4*)&xr[nb];
    float4 h1 = *(const float4*)&xr[nb + 4];
    U4 A0, A1, Bf;
    A0.u.x = pk(f0.x, f0.y); A0.u.y = pk(f0.z, f0.w);
    A0.u.z = pk(f1.x, f1.y); A0.u.w = pk(f1.z, f1.w);
    A1.u.x = pk(g0.x, g0.y); A1.u.y = pk(g0.z, g0.w);
    A1.u.z = pk(g1.x, g1.y); A1.u.w = pk(g1.z, g1.w);
    Bf.u.x = pk(h0.x, h0.y); Bf.u.y = pk(h0.z, h0.w);
    Bf.u.z = pk(h1.x, h1.y); Bf.u.w = pk(h1.z, h1.w);
    acc[0] = __builtin_amdgcn_mfma_f32_32x32x16_bf16(A0.b, Bf.b, acc[0], 0, 0, 0);
    acc[1] = __builtin_amdgcn_mfma_f32_32x32x16_bf16(A1.b, Bf.b, acc[1], 0, 0, 0);
  }
  // stash per-wave partials
#pragma unroll
  for (int kt = 0; kt < 2; kt++)
#pragma unroll
    for (int q = 0; q < 4; q++) {
      float4 vv = make_float4(acc[kt][q * 4], acc[kt][q * 4 + 1],
                              acc[kt][q * 4 + 2], acc[kt][q * 4 + 3]);
      *(float4*)&red[wid][lane][kt * 16 + q * 4] = vv;
    }
  __syncthreads();
  // cross-wave reduce + write (2048 outputs, 8 per thread)
  float* wxp = z ? wxp1 : wxp0;
  const int lt = tid & 63, sb4 = (tid >> 6) * 8;
  float v[8];
#pragma unroll
  for (int i = 0; i < 8; i++) v[i] = 0.f;
#pragma unroll
  for (int w = 0; w < 4; w++)
#pragma unroll
    for (int i = 0; i < 8; i++) v[i] += red[w][lt][sb4 + i];
#pragma unroll
  for (int i = 0; i < 8; i++) {
    int s = sb4 + i;
    int kt = s >> 4, r = s & 15;
    int k = kt * 32 + (r & 3) + 8 * (r >> 2) + 4 * (lt >> 5);
    wxp[((size_t)b * K_ + k) * C_ + c0 + (lt & 31)] = v[i];
  }
}

// ---------------------------------------------------------------- kernel 4
// nodes = (wx - wsum*anchor)/sigma/(wsum+eps); intra L2-norm -> out0; gsum.
// Sums the two k_agg partials (wxp0 aliases out0 region; reads precede
// the out0 writes within each block, so the alias is safe).
__global__ void k_nodes(const float* __restrict__ wxp0,
                        const float* __restrict__ wxp1,
                        const float* __restrict__ wsum,
                        const float* __restrict__ anchor,
                        const float* __restrict__ invsig,
                        float* __restrict__ out0,
                        float* __restrict__ gsum) {
  const int k = blockIdx.x, b = blockIdx.y;
  const int tid = threadIdx.x;
  float wsv = wsum[b * K_ + k];
  float winv = 1.f / (wsv + 1e-9f);
  float vals[4];
  float local = 0.f;
#pragma unroll
  for (int r = 0; r < 4; r++) {
    int c = r * 128 + tid;
    size_t idx = ((size_t)b * K_ + k) * C_ + c;
    float w = wxp0[idx] + wxp1[idx];
    float v = (w - wsv * anchor[k * C_ + c]) * invsig[k * C_ + c] * winv;
    vals[r] = v;
    local = fmaf(v, v, local);
  }
  float v = local;
#pragma unroll
  for (int off = 32; off; off >>= 1) v += __shfl_down(v, off);
  __shared__ float red[2];
  if ((tid & 63) == 0) red[tid >> 6] = v;
  __syncthreads();
  float sumsq = red[0] + red[1];
  float norm = sqrtf(sumsq);
  float scale = 1.f / fmaxf(norm, 1e-12f);
#pragma unroll
  for (int r = 0; r < 4; r++) {
    int c = r * 128 + tid;
    out0[((size_t)b * K_ + k) * C_ + c] = vals[r] * scale;
  }
  if (tid == 0) atomicAdd(&gsum[b], sumsq * scale * scale);
}

// ---------------------------------------------------------------- kernel 5
// Global L2 scale in place on out0 ([B][K*C] flat == reference (B,C,K)).
__global__ void k_final(float* __restrict__ out0,
                        const float* __restrict__ gsum) {
  for (int i = blockIdx.x * 256 + threadIdx.x; i < B_ * K_ * C_;
       i += gridDim.x * 256) {
    int b = i >> 15;  // K_*C_ = 32768
    out0[i] = out0[i] * (1.f / fmaxf(sqrtf(gsum[b]), 1e-12f));
  }
}

// ---------------------------------------------------------------- launch
extern "C" void kernel_launch(void* const* d_in, const int* in_sizes, int n_in,
                              void* d_out, int out_size, void* d_ws, size_t ws_size,
                              hipStream_t stream) {
  const float* x = (const float*)d_in[0];       // [B,C,H,W]
  const float* anchor = (const float*)d_in[1];  // [K,C]
  const float* sraw = (const float*)d_in[2];    // [K,C]
  float* out0 = (float*)d_out;                          // [B,C,K] flat
  float* soft = out0 + (size_t)B_ * C_ * K_;            // [B,K,N] (output 1)
  float* ws = (float*)d_ws;

  unsigned* pbig = (unsigned*)(ws + OFF_PBIG);
  float* invsig = ws + OFF_INVSIG;
  float* wsum = ws + OFF_WSUM;
  float* gsum = ws + OFF_GSUM;
  float* wx1 = ws + OFF_WX;   // k_agg partial z=1
  float* wx0 = out0;          // k_agg partial z=0 (aliases out0; see k_nodes)

  k_prep<<<K_, 256, 0, stream>>>(anchor, sraw, pbig, invsig, wsum, gsum);
  k_dist<<<dim3(N_ / 128, B_), 256, 0, stream>>>(x, pbig, soft, wsum);
  k_agg<<<dim3(C_ / 32, B_, 2), 256, 0, stream>>>(x, soft, wx0, wx1);
  k_nodes<<<dim3(K_, B_), 128, 0, stream>>>(wx0, wx1, wsum, anchor, invsig,
                                            out0, gsum);
  k_final<<<512, 256, 0, stream>>>(out0, gsum);
}

// Round 4
// 349.274 us; speedup vs baseline: 1.2027x; 1.2027x over previous
//
#include <hip/hip_runtime.h>
#include <math.h>

// Problem constants (fixed by reference setup_inputs)
#define B_ 16
#define C_ 512
#define N_ 4096   // 64*64
#define K_ 64

// Workspace layout (float offsets). Total ~689K floats = 2.76 MB.
#define OFF_PBIG    0         // [64 k][2048 dwords] bf16-pair packed param matrix (r = c*8+f)
#define OFF_INVSIG  131072    // [K][C] 1/sigma fp32
#define OFF_WSUM    163840    // [B][K]
#define OFF_GSUM    164864    // [B]
#define OFF_WX      164992    // [B][K][C] fp32 partial-1 (partial-0 aliases out0)

typedef short bf16x8 __attribute__((ext_vector_type(8)));   // 8 bf16 in 4 VGPRs
typedef float f32x16 __attribute__((ext_vector_type(16)));  // MFMA 32x32 accumulator

union U4 { uint4 u; bf16x8 b; };

__device__ __forceinline__ unsigned hi16(float f) { return __float_as_uint(f) >> 16; }
__device__ __forceinline__ unsigned hi16rne(float f) {
  return (__float_as_uint(f) + 0x8000u) >> 16;
}
__device__ __forceinline__ float fromhi(unsigned h) { return __uint_as_float(h << 16); }
// pack two floats' truncated-bf16 into one dword: low16 = bf16(lo), high16 = bf16(hi)
__device__ __forceinline__ unsigned pk(float lo, float hi) {
  return (__float_as_uint(lo) >> 16) | (__float_as_uint(hi) & 0xFFFF0000u);
}

// ---------------------------------------------------------------- kernel 1
// Build pbig, invsig; zero wsum/gsum. One block per k.
__global__ void k_prep(const float* __restrict__ anchor,
                       const float* __restrict__ sraw,
                       unsigned* __restrict__ pbig,
                       float* __restrict__ invsig,
                       float* __restrict__ wsum,
                       float* __restrict__ gsum) {
  const int k = blockIdx.x;
  const int t = threadIdx.x;
  __shared__ float s_is2[C_], s_m[C_];
  __shared__ float red[4];
  float part = 0.f;
#pragma unroll
  for (int r = 0; r < 2; r++) {
    int c = r * 256 + t;
    float a = anchor[k * C_ + c];
    float sg = 1.f / (1.f + __expf(-sraw[k * C_ + c]));
    float is = 1.f / sg;
    float is2 = is * is;
    s_is2[c] = is2;
    s_m[c] = -2.f * a * is2;
    invsig[k * C_ + c] = is;
    part = fmaf(a * a, is2, part);
  }
  float v = part;
#pragma unroll
  for (int off = 32; off; off >>= 1) v += __shfl_down(v, off);
  if ((t & 63) == 0) red[t >> 6] = v;
  __syncthreads();
  float cst = red[0] + red[1] + red[2] + red[3];
  unsigned ch = hi16(cst);
  unsigned clr = hi16rne(cst - fromhi(ch));
#pragma unroll
  for (int r = 0; r < 2; r++) {
    int c = r * 256 + t;
    float is2 = s_is2[c], m = s_m[c];
    unsigned ih = hi16(is2);
    unsigned ilr = hi16rne(is2 - fromhi(ih));
    unsigned mh = hi16(m);
    unsigned mlr = hi16rne(m - fromhi(mh));
    unsigned* p = pbig + (size_t)k * 2048 + c * 4;
    p[0] = ih | (ilr << 16);
    p[1] = ih | (mh << 16);
    p[2] = mlr | (mh << 16);
    p[3] = (c == 0) ? (ch | (clr << 16)) : 0u;
  }
  if (k == 0) {
    for (int i = t; i < B_ * K_; i += 256) wsum[i] = 0.f;
    if (t < B_) gsum[t] = 0.f;
  }
}

// ---------------------------------------------------------------- kernel 2
// MFMA distance GEMM (split-bf16, inner dim 4096) + in-register softmax.
// v4: latency-chain fix. Wave tile 64k x 32n (acc0/acc1, all-static).
//  - 16 x-loads per chunk hoisted into xreg[16] BEFORE LDS staging: 16
//    independent loads in flight, latency hidden under staging+barrier.
//    (v1-v3 issued 1-2 scalar loads at a time inside the MFMA loop: the
//    ~500cy serial chain explains the 13%-util plateau.)
//  - LDS = one 33.8 KB region -> 4 blocks/CU = 16 waves/CU (v1 had 4).
//  - 1D grid 512, XCD-swizzled (512%8==0, bijective).
__global__ __launch_bounds__(256) void k_dist(
    const float* __restrict__ x,
    const unsigned* __restrict__ pbig,
    float* __restrict__ soft,
    float* __restrict__ wsum) {
  const int bid = blockIdx.x;
  const int swz = (bid & 7) * 64 + (bid >> 3);   // XCD-contiguous remap
  const int b = swz >> 5;                        // 16 batches
  const int nblk = (swz & 31) * 128;             // 32 n-blocks of 128
  const int tid = threadIdx.x;
  const int wid = tid >> 6;
  const int lane = tid & 63;
  const int l31 = lane & 31;
  const int lh = lane >> 5;
  const int n0 = nblk + wid * 32;

  __shared__ unsigned ldsA[64 * 132];  // row stride 132 dw = 528 B

  f32x16 acc0, acc1;
#pragma unroll
  for (int i = 0; i < 16; i++) { acc0[i] = 0.f; acc1[i] = 0.f; }

  const float* xb = x + (size_t)b * (C_ * N_);
  const float* xcol = xb + n0 + l31;   // this lane's n-column base

  for (int chunk = 0; chunk < 16; chunk++) {
    // ---- hoist this chunk's 16 x loads (independent of LDS) ----
    float xreg[16];
#pragma unroll
    for (int kk = 0; kk < 16; kk++)
      xreg[kk] = xcol[(size_t)(chunk * 32 + kk * 2 + lh) * N_];
    // ---- stage pbig chunk (64 k rows x 128 dwords) into LDS ----
    const uint4* src = (const uint4*)pbig;
#pragma unroll
    for (int it = 0; it < 8; it++) {
      int flat = tid + it * 256;       // 0..2047
      int k = flat >> 5, q = flat & 31;
      uint4 vv = src[(size_t)k * 512 + chunk * 32 + q];
      *(uint4*)&ldsA[k * 132 + q * 4] = vv;
    }
    __syncthreads();
#pragma unroll
    for (int kstep = 0; kstep < 16; kstep++) {
      U4 a0, a1;
      a0.u = *(const uint4*)&ldsA[l31 * 132 + kstep * 8 + lh * 4];
      a1.u = *(const uint4*)&ldsA[(32 + l31) * 132 + kstep * 8 + lh * 4];
      const int c = chunk * 32 + kstep * 2 + lh;
      float xv = xreg[kstep];
      float x2 = xv * xv;
      unsigned u = __float_as_uint(xv);
      unsigned u2 = __float_as_uint(x2);
      unsigned uhf = u & 0xFFFF0000u;
      unsigned u2hf = u2 & 0xFFFF0000u;
      float xl = xv - __uint_as_float(uhf);
      float x2l = x2 - __uint_as_float(u2hf);
      U4 bf;
      bf.u.x = (u2 >> 16) | u2hf;                                   // x2h | x2h
      bf.u.y = ((__float_as_uint(x2l) + 0x8000u) >> 16) | uhf;      // x2l | xh
      bf.u.z = (u >> 16) | ((__float_as_uint(xl) + 0x8000u) & 0xFFFF0000u); // xh | xl
      bf.u.w = (c == 0) ? 0x3F803F80u : 0u;                         // 1.0 | 1.0 @ c==0
      acc0 = __builtin_amdgcn_mfma_f32_32x32x16_bf16(a0.b, bf.b, acc0, 0, 0, 0);
      acc1 = __builtin_amdgcn_mfma_f32_32x32x16_bf16(a1.b, bf.b, acc1, 0, 0, 0);
    }
    __syncthreads();
  }

  // ---- per-wave softmax over k=64 for this lane's column (lane & lane^32
  // hold complementary k halves; all register indices static) ----
  float* softb = soft + (size_t)b * (K_ * N_);
  float mm = -3.4e38f;
#pragma unroll
  for (int r = 0; r < 16; r++) {
    acc0[r] *= -0.5f; mm = fmaxf(mm, acc0[r]);
    acc1[r] *= -0.5f; mm = fmaxf(mm, acc1[r]);
  }
  mm = fmaxf(mm, __shfl_xor(mm, 32));
  float ss = 0.f;
#pragma unroll
  for (int r = 0; r < 16; r++) {
    acc0[r] = __expf(acc0[r] - mm); ss += acc0[r];
    acc1[r] = __expf(acc1[r] - mm); ss += acc1[r];
  }
  ss += __shfl_xor(ss, 32);
  float inv = 1.f / ss;
  const int nc = n0 + l31;
#pragma unroll
  for (int r = 0; r < 16; r++) {
    int k0 = (r & 3) + 8 * (r >> 2) + 4 * lh;
    float w0 = acc0[r] * inv; acc0[r] = w0;
    softb[(size_t)k0 * N_ + nc] = w0;
    float w1 = acc1[r] * inv; acc1[r] = w1;
    softb[(size_t)(32 + k0) * N_ + nc] = w1;
  }
  // ---- wsum: reduce over this wave's 32 n-columns, atomics from l31==0 ----
#pragma unroll
  for (int r = 0; r < 16; r++) {
    float v0 = acc0[r];
    v0 += __shfl_xor(v0, 1);
    v0 += __shfl_xor(v0, 2);
    v0 += __shfl_xor(v0, 4);
    v0 += __shfl_xor(v0, 8);
    v0 += __shfl_xor(v0, 16);
    float v1 = acc1[r];
    v1 += __shfl_xor(v1, 1);
    v1 += __shfl_xor(v1, 2);
    v1 += __shfl_xor(v1, 4);
    v1 += __shfl_xor(v1, 8);
    v1 += __shfl_xor(v1, 16);
    if (l31 == 0) {
      int k0 = (r & 3) + 8 * (r >> 2) + 4 * lh;
      atomicAdd(&wsum[b * K_ + k0], v0);
      atomicAdd(&wsum[b * K_ + 32 + k0], v1);
    }
  }
}

// ---------------------------------------------------------------- kernel 3
// Aggregation GEMM via MFMA: wx[b,k,c] = sum_n soft[b,k,n]*x[b,c,n].
// grid (C/32, B, 2) -- n split in half across blockIdx.z, partials go to
// two buffers (z=0 aliases out0 region; z=1 in ws). 512 blocks -> 2/CU.
__global__ __launch_bounds__(256) void k_agg(const float* __restrict__ x,
                                             const float* __restrict__ soft,
                                             float* __restrict__ wxp0,
                                             float* __restrict__ wxp1) {
  const int ct = blockIdx.x;
  const int b = blockIdx.y;
  const int z = blockIdx.z;
  const int tid = threadIdx.x;
  const int wid = tid >> 6, lane = tid & 63, l31 = lane & 31, lh = lane >> 5;
  const int c0 = ct * 32;
  const int n0 = z * 2048 + wid * 512;
  __shared__ float red[4][64][36];  // stride 36 floats = 9x16B (odd) per lane

  f32x16 acc[2];
#pragma unroll
  for (int kt = 0; kt < 2; kt++)
#pragma unroll
    for (int i = 0; i < 16; i++) acc[kt][i] = 0.f;

  const float* sb = soft + (size_t)b * (K_ * N_);
  const float* xr = x + (size_t)b * (C_ * N_) + (size_t)(c0 + l31) * N_;
  const float* s0 = sb + (size_t)l31 * N_;
  const float* s1 = sb + (size_t)(32 + l31) * N_;

  for (int kstep = 0; kstep < 32; kstep++) {
    int nb = n0 + kstep * 16 + lh * 8;
    float4 f0 = *(const float4*)&s0[nb];
    float4 f1 = *(const float4*)&s0[nb + 4];
    float4 g0 = *(const float4*)&s1[nb];
    float4 g1 = *(const float4*)&s1[nb + 4];
    float4 h0 = *(const float4*)&xr[nb];
    float4 h1 = *(const float4*)&xr[nb + 4];
    U4 A0, A1, Bf;
    A0.u.x = pk(f0.x, f0.y); A0.u.y = pk(f0.z, f0.w);
    A0.u.z = pk(f1.x, f1.y); A0.u.w = pk(f1.z, f1.w);
    A1.u.x = pk(g0.x, g0.y); A1.u.y = pk(g0.z, g0.w);
    A1.u.z = pk(g1.x, g1.y); A1.u.w = pk(g1.z, g1.w);
    Bf.u.x = pk(h0.x, h0.y); Bf.u.y = pk(h0.z, h0.w);
    Bf.u.z = pk(h1.x, h1.y); Bf.u.w = pk(h1.z, h1.w);
    acc[0] = __builtin_amdgcn_mfma_f32_32x32x16_bf16(A0.b, Bf.b, acc[0], 0, 0, 0);
    acc[1] = __builtin_amdgcn_mfma_f32_32x32x16_bf16(A1.b, Bf.b, acc[1], 0, 0, 0);
  }
  // stash per-wave partials
#pragma unroll
  for (int kt = 0; kt < 2; kt++)
#pragma unroll
    for (int q = 0; q < 4; q++) {
      float4 vv = make_float4(acc[kt][q * 4], acc[kt][q * 4 + 1],
                              acc[kt][q * 4 + 2], acc[kt][q * 4 + 3]);
      *(float4*)&red[wid][lane][kt * 16 + q * 4] = vv;
    }
  __syncthreads();
  // cross-wave reduce + write (2048 outputs, 8 per thread)
  float* wxp = z ? wxp1 : wxp0;
  const int lt = tid & 63, sb4 = (tid >> 6) * 8;
  float v[8];
#pragma unroll
  for (int i = 0; i < 8; i++) v[i] = 0.f;
#pragma unroll
  for (int w = 0; w < 4; w++)
#pragma unroll
    for (int i = 0; i < 8; i++) v[i] += red[w][lt][sb4 + i];
#pragma unroll
  for (int i = 0; i < 8; i++) {
    int s = sb4 + i;
    int kt = s >> 4, r = s & 15;
    int k = kt * 32 + (r & 3) + 8 * (r >> 2) + 4 * (lt >> 5);
    wxp[((size_t)b * K_ + k) * C_ + c0 + (lt & 31)] = v[i];
  }
}

// ---------------------------------------------------------------- kernel 4
// nodes = (wx - wsum*anchor)/sigma/(wsum+eps); intra L2-norm -> out0; gsum.
// Sums the two k_agg partials (wxp0 aliases out0 region; reads precede
// the out0 writes within each block, so the alias is safe).
__global__ void k_nodes(const float* __restrict__ wxp0,
                        const float* __restrict__ wxp1,
                        const float* __restrict__ wsum,
                        const float* __restrict__ anchor,
                        const float* __restrict__ invsig,
                        float* __restrict__ out0,
                        float* __restrict__ gsum) {
  const int k = blockIdx.x, b = blockIdx.y;
  const int tid = threadIdx.x;
  float wsv = wsum[b * K_ + k];
  float winv = 1.f / (wsv + 1e-9f);
  float vals[4];
  float local = 0.f;
#pragma unroll
  for (int r = 0; r < 4; r++) {
    int c = r * 128 + tid;
    size_t idx = ((size_t)b * K_ + k) * C_ + c;
    float w = wxp0[idx] + wxp1[idx];
    float v = (w - wsv * anchor[k * C_ + c]) * invsig[k * C_ + c] * winv;
    vals[r] = v;
    local = fmaf(v, v, local);
  }
  float v = local;
#pragma unroll
  for (int off = 32; off; off >>= 1) v += __shfl_down(v, off);
  __shared__ float red[2];
  if ((tid & 63) == 0) red[tid >> 6] = v;
  __syncthreads();
  float sumsq = red[0] + red[1];
  float norm = sqrtf(sumsq);
  float scale = 1.f / fmaxf(norm, 1e-12f);
#pragma unroll
  for (int r = 0; r < 4; r++) {
    int c = r * 128 + tid;
    out0[((size_t)b * K_ + k) * C_ + c] = vals[r] * scale;
  }
  if (tid == 0) atomicAdd(&gsum[b], sumsq * scale * scale);
}

// ---------------------------------------------------------------- kernel 5
// Global L2 scale in place on out0 ([B][K*C] flat == reference (B,C,K)).
__global__ void k_final(float* __restrict__ out0,
                        const float* __restrict__ gsum) {
  for (int i = blockIdx.x * 256 + threadIdx.x; i < B_ * K_ * C_;
       i += gridDim.x * 256) {
    int b = i >> 15;  // K_*C_ = 32768
    out0[i] = out0[i] * (1.f / fmaxf(sqrtf(gsum[b]), 1e-12f));
  }
}

// ---------------------------------------------------------------- launch
extern "C" void kernel_launch(void* const* d_in, const int* in_sizes, int n_in,
                              void* d_out, int out_size, void* d_ws, size_t ws_size,
                              hipStream_t stream) {
  const float* x = (const float*)d_in[0];       // [B,C,H,W]
  const float* anchor = (const float*)d_in[1];  // [K,C]
  const float* sraw = (const float*)d_in[2];    // [K,C]
  float* out0 = (float*)d_out;                          // [B,C,K] flat
  float* soft = out0 + (size_t)B_ * C_ * K_;            // [B,K,N] (output 1)
  float* ws = (float*)d_ws;

  unsigned* pbig = (unsigned*)(ws + OFF_PBIG);
  float* invsig = ws + OFF_INVSIG;
  float* wsum = ws + OFF_WSUM;
  float* gsum = ws + OFF_GSUM;
  float* wx1 = ws + OFF_WX;   // k_agg partial z=1
  float* wx0 = out0;          // k_agg partial z=0 (aliases out0; see k_nodes)

  k_prep<<<K_, 256, 0, stream>>>(anchor, sraw, pbig, invsig, wsum, gsum);
  k_dist<<<512, 256, 0, stream>>>(x, pbig, soft, wsum);
  k_agg<<<dim3(C_ / 32, B_, 2), 256, 0, stream>>>(x, soft, wx0, wx1);
  k_nodes<<<dim3(K_, B_), 128, 0, stream>>>(wx0, wx1, wsum, anchor, invsig,
                                            out0, gsum);
  k_final<<<512, 256, 0, stream>>>(out0, gsum);
}

// Round 5
// 328.571 us; speedup vs baseline: 1.2784x; 1.0630x over previous
//
#include <hip/hip_runtime.h>
#include <math.h>

// Problem constants (fixed by reference setup_inputs)
#define B_ 16
#define C_ 512
#define N_ 4096   // 64*64
#define K_ 64

// Workspace layout (float offsets). Total ~689K floats = 2.76 MB.
#define OFF_PBIG    0         // [16 chunk][16 kstep][2 kh][64 lane] uint4 = 512 KB
#define OFF_INVSIG  131072    // [K][C] 1/sigma fp32
#define OFF_WSUM    163840    // [B][K]
#define OFF_GSUM    164864    // [B]
#define OFF_WX      164992    // [B][K][C] fp32, atomic-accumulated by k_agg

typedef short bf16x8 __attribute__((ext_vector_type(8)));   // 8 bf16 in 4 VGPRs
typedef float f32x16 __attribute__((ext_vector_type(16)));  // MFMA 32x32 accumulator

union U4 { uint4 u; bf16x8 b; };

__device__ __forceinline__ unsigned hi16(float f) { return __float_as_uint(f) >> 16; }
__device__ __forceinline__ unsigned hi16rne(float f) {
  return (__float_as_uint(f) + 0x8000u) >> 16;
}
__device__ __forceinline__ float fromhi(unsigned h) { return __uint_as_float(h << 16); }
// pack two floats' truncated-bf16 into one dword: low16 = bf16(lo), high16 = bf16(hi)
__device__ __forceinline__ unsigned pk(float lo, float hi) {
  return (__float_as_uint(lo) >> 16) | (__float_as_uint(hi) & 0xFFFF0000u);
}

// ---------------------------------------------------------------- kernel 1
// Build pbig (MFMA-fragment order), invsig; zero wsum/gsum/wx. One block per k.
// pbig uint4 index for (k,c): chunk=c>>5, ks=(c&31)>>1, lh=c&1, kh=k>>5:
//   (((chunk*16+ks)*2+kh)*64 + lh*32 + (k&31))
// so a wave's A-fragment load in k_dist is one coalesced uint4 per lane.
__global__ void k_prep(const float* __restrict__ anchor,
                       const float* __restrict__ sraw,
                       unsigned* __restrict__ pbig,
                       float* __restrict__ invsig,
                       float* __restrict__ wsum,
                       float* __restrict__ gsum,
                       float* __restrict__ wx) {
  const int k = blockIdx.x;
  const int t = threadIdx.x;
  __shared__ float s_is2[C_], s_m[C_];
  __shared__ float red[4];
  float part = 0.f;
#pragma unroll
  for (int r = 0; r < 2; r++) {
    int c = r * 256 + t;
    float a = anchor[k * C_ + c];
    float sg = 1.f / (1.f + __expf(-sraw[k * C_ + c]));
    float is = 1.f / sg;
    float is2 = is * is;
    s_is2[c] = is2;
    s_m[c] = -2.f * a * is2;
    invsig[k * C_ + c] = is;
    part = fmaf(a * a, is2, part);
  }
  float v = part;
#pragma unroll
  for (int off = 32; off; off >>= 1) v += __shfl_down(v, off);
  if ((t & 63) == 0) red[t >> 6] = v;
  __syncthreads();
  float cst = red[0] + red[1] + red[2] + red[3];
  unsigned ch = hi16(cst);
  unsigned clr = hi16rne(cst - fromhi(ch));
#pragma unroll
  for (int r = 0; r < 2; r++) {
    int c = r * 256 + t;
    float is2 = s_is2[c], m = s_m[c];
    unsigned ih = hi16(is2);
    unsigned ilr = hi16rne(is2 - fromhi(ih));
    unsigned mh = hi16(m);
    unsigned mlr = hi16rne(m - fromhi(mh));
    int chunk = c >> 5, ks = (c & 31) >> 1, lh = c & 1;
    int kh = k >> 5;
    size_t dst = ((((size_t)chunk * 16 + ks) * 2 + kh) * 64 + lh * 32 + (k & 31)) * 4;
    pbig[dst + 0] = ih | (ilr << 16);
    pbig[dst + 1] = ih | (mh << 16);
    pbig[dst + 2] = mlr | (mh << 16);
    pbig[dst + 3] = (c == 0) ? (ch | (clr << 16)) : 0u;
  }
  // zero wx slice for this k-block: 8192 floats = 2048 float4
  float4 z4 = make_float4(0.f, 0.f, 0.f, 0.f);
  float4* wz = (float4*)(wx + (size_t)k * 8192);
#pragma unroll
  for (int it = 0; it < 8; it++) wz[it * 256 + t] = z4;
  if (k == 0) {
    for (int i = t; i < B_ * K_; i += 256) wsum[i] = 0.f;
    if (t < B_) gsum[t] = 0.f;
  }
}

// ---------------------------------------------------------------- kernel 2
// MFMA distance GEMM (split-bf16, inner dim 4096) + softmax.
// v5: NO LDS staging, NO per-chunk barriers. A-fragments are read directly
// from L2-resident pbig (fragment-ordered, one coalesced uint4/lane/kstep).
// k split across wave pairs: wave tile 32k x 32n, 1 MFMA/kstep. Grid 1024
// blocks x 4 waves = 4096 waves = 4/SIMD (v4 was structurally capped at 2).
// x loads explicitly double-buffered (xa/xb_, all-static indices).
__global__ __launch_bounds__(256, 4) void k_dist(
    const float* __restrict__ x,
    const unsigned* __restrict__ pbig,
    float* __restrict__ soft,
    float* __restrict__ wsum) {
  const int bid = blockIdx.x;
  const int swz = (bid & 7) * 128 + (bid >> 3);  // XCD-contiguous remap (bijective)
  const int b = swz >> 6;                        // 16 batches
  const int nblk = (swz & 63) * 64;              // 64 n-blocks of 64
  const int tid = threadIdx.x;
  const int wid = tid >> 6;
  const int lane = tid & 63;
  const int l31 = lane & 31;
  const int lh = lane >> 5;
  const int kh = wid & 1;                        // this wave's k-half
  const int n0 = nblk + (wid >> 1) * 32;

  __shared__ float cmax[4][32];
  __shared__ float csum[4][32];

  f32x16 acc;
#pragma unroll
  for (int i = 0; i < 16; i++) acc[i] = 0.f;

  const float* xcol = x + (size_t)b * (C_ * N_) + n0 + l31;
  const uint4* pf = (const uint4*)pbig + (size_t)kh * 64 + lane;

  float xa[16], xb_[16];
#pragma unroll
  for (int kk = 0; kk < 16; kk++)
    xa[kk] = xcol[(size_t)(kk * 2 + lh) * N_];

#define PACKMF(XV, CC, ACC, AFRAG)                                            \
  {                                                                           \
    float xv = (XV);                                                          \
    float x2 = xv * xv;                                                       \
    unsigned u = __float_as_uint(xv);                                         \
    unsigned u2 = __float_as_uint(x2);                                        \
    unsigned uhf = u & 0xFFFF0000u;                                           \
    unsigned u2hf = u2 & 0xFFFF0000u;                                         \
    float xl = xv - __uint_as_float(uhf);                                     \
    float x2l = x2 - __uint_as_float(u2hf);                                   \
    U4 bf;                                                                    \
    bf.u.x = (u2 >> 16) | u2hf;                                               \
    bf.u.y = ((__float_as_uint(x2l) + 0x8000u) >> 16) | uhf;                  \
    bf.u.z = (u >> 16) | ((__float_as_uint(xl) + 0x8000u) & 0xFFFF0000u);     \
    bf.u.w = ((CC) == 0) ? 0x3F803F80u : 0u;                                  \
    ACC = __builtin_amdgcn_mfma_f32_32x32x16_bf16((AFRAG), bf.b, ACC, 0, 0, 0); \
  }

  for (int c2 = 0; c2 < 8; c2++) {
    {  // body A: chunk = 2*c2, consumes xa, prefetches xb_
      const int chunk = 2 * c2;
#pragma unroll
      for (int kk = 0; kk < 16; kk++)
        xb_[kk] = xcol[(size_t)((chunk + 1) * 32 + kk * 2 + lh) * N_];
#pragma unroll
      for (int ks = 0; ks < 16; ks++) {
        U4 a;
        a.u = pf[(size_t)(chunk * 16 + ks) * 128];
        PACKMF(xa[ks], chunk * 32 + ks * 2 + lh, acc, a.b);
      }
    }
    {  // body B: chunk = 2*c2+1, consumes xb_, prefetches xa
      const int chunk = 2 * c2 + 1;
      if (c2 < 7) {
#pragma unroll
        for (int kk = 0; kk < 16; kk++)
          xa[kk] = xcol[(size_t)((chunk + 1) * 32 + kk * 2 + lh) * N_];
      }
#pragma unroll
      for (int ks = 0; ks < 16; ks++) {
        U4 a;
        a.u = pf[(size_t)(chunk * 16 + ks) * 128];
        PACKMF(xb_[ks], chunk * 32 + ks * 2 + lh, acc, a.b);
      }
    }
  }
#undef PACKMF

  // ---- softmax over k=64: in-wave (32 rows via lane^32) then cross-wave
  // (k-half partner wid^1) via tiny LDS max/sum arrays. ----
  float* softb = soft + (size_t)b * (K_ * N_);
  float mm = -3.4e38f;
#pragma unroll
  for (int r = 0; r < 16; r++) {
    acc[r] *= -0.5f;
    mm = fmaxf(mm, acc[r]);
  }
  mm = fmaxf(mm, __shfl_xor(mm, 32));
  cmax[wid][l31] = mm;
  __syncthreads();
  float m = fmaxf(cmax[wid][l31], cmax[wid ^ 1][l31]);
  float ss = 0.f;
#pragma unroll
  for (int r = 0; r < 16; r++) {
    acc[r] = __expf(acc[r] - m);
    ss += acc[r];
  }
  ss += __shfl_xor(ss, 32);
  csum[wid][l31] = ss;
  __syncthreads();
  float tot = csum[wid][l31] + csum[wid ^ 1][l31];
  float inv = 1.f / tot;
  const int nc = n0 + l31;
#pragma unroll
  for (int r = 0; r < 16; r++) {
    float w = acc[r] * inv;
    acc[r] = w;
    int k0 = kh * 32 + (r & 3) + 8 * (r >> 2) + 4 * lh;
    softb[(size_t)k0 * N_ + nc] = w;
  }
  // ---- wsum: reduce own 32 n-columns, one atomic per k-row ----
#pragma unroll
  for (int r = 0; r < 16; r++) {
    float v = acc[r];
    v += __shfl_xor(v, 1);
    v += __shfl_xor(v, 2);
    v += __shfl_xor(v, 4);
    v += __shfl_xor(v, 8);
    v += __shfl_xor(v, 16);
    if (l31 == 0) {
      int k0 = kh * 32 + (r & 3) + 8 * (r >> 2) + 4 * lh;
      atomicAdd(&wsum[b * K_ + k0], v);
    }
  }
}

// ---------------------------------------------------------------- kernel 3
// Aggregation GEMM via MFMA: wx[b,k,c] += sum_n soft[b,k,n]*x[b,c,n].
// v5: n split 4 ways (z), grid 1024 1D with XCD-group swizzle so each (b,z)
// group's soft slice is HBM-read once per XCD. Partials atomicAdd'ed into
// the single zero-initialized wx (4-way contention, negligible).
__global__ __launch_bounds__(256, 4) void k_agg(const float* __restrict__ x,
                                                const float* __restrict__ soft,
                                                float* __restrict__ wx) {
  const int bid = blockIdx.x;
  const int xcd = bid & 7, slot = bid >> 3;      // 128 slots per XCD
  const int grp = (slot >> 4) * 8 + xcd;         // 0..63 = (b,z) group
  const int ct = slot & 15;
  const int b = grp & 15, z = grp >> 4;
  const int tid = threadIdx.x;
  const int wid = tid >> 6, lane = tid & 63, l31 = lane & 31, lh = lane >> 5;
  const int c0 = ct * 32;
  const int n0 = z * 1024 + wid * 256;
  __shared__ float red[4][64][36];  // stride 36 floats (odd x16B) per lane

  f32x16 acc[2];
#pragma unroll
  for (int kt = 0; kt < 2; kt++)
#pragma unroll
    for (int i = 0; i < 16; i++) acc[kt][i] = 0.f;

  const float* sb = soft + (size_t)b * (K_ * N_);
  const float* xr = x + (size_t)b * (C_ * N_) + (size_t)(c0 + l31) * N_;
  const float* s0 = sb + (size_t)l31 * N_;
  const float* s1 = sb + (size_t)(32 + l31) * N_;

  for (int kstep = 0; kstep < 16; kstep++) {
    int nb = n0 + kstep * 16 + lh * 8;
    float4 f0 = *(const float4*)&s0[nb];
    float4 f1 = *(const float4*)&s0[nb + 4];
    float4 g0 = *(const float4*)&s1[nb];
    float4 g1 = *(const float4*)&s1[nb + 4];
    float4 h0 = *(const float4*)&xr[nb];
    float4 h1 = *(const float4*)&xr[nb + 4];
    U4 A0, A1, Bf;
    A0.u.x = pk(f0.x, f0.y); A0.u.y = pk(f0.z, f0.w);
    A0.u.z = pk(f1.x, f1.y); A0.u.w = pk(f1.z, f1.w);
    A1.u.x = pk(g0.x, g0.y); A1.u.y = pk(g0.z, g0.w);
    A1.u.z = pk(g1.x, g1.y); A1.u.w = pk(g1.z, g1.w);
    Bf.u.x = pk(h0.x, h0.y); Bf.u.y = pk(h0.z, h0.w);
    Bf.u.z = pk(h1.x, h1.y); Bf.u.w = pk(h1.z, h1.w);
    acc[0] = __builtin_amdgcn_mfma_f32_32x32x16_bf16(A0.b, Bf.b, acc[0], 0, 0, 0);
    acc[1] = __builtin_amdgcn_mfma_f32_32x32x16_bf16(A1.b, Bf.b, acc[1], 0, 0, 0);
  }
  // stash per-wave partials
#pragma unroll
  for (int kt = 0; kt < 2; kt++)
#pragma unroll
    for (int q = 0; q < 4; q++) {
      float4 vv = make_float4(acc[kt][q * 4], acc[kt][q * 4 + 1],
                              acc[kt][q * 4 + 2], acc[kt][q * 4 + 3]);
      *(float4*)&red[wid][lane][kt * 16 + q * 4] = vv;
    }
  __syncthreads();
  // cross-wave reduce + atomic accumulate (2048 outputs, 8 per thread)
  const int lt = tid & 63, sb4 = (tid >> 6) * 8;
  float v[8];
#pragma unroll
  for (int i = 0; i < 8; i++) v[i] = 0.f;
#pragma unroll
  for (int w = 0; w < 4; w++)
#pragma unroll
    for (int i = 0; i < 8; i++) v[i] += red[w][lt][sb4 + i];
#pragma unroll
  for (int i = 0; i < 8; i++) {
    int s = sb4 + i;
    int kt = s >> 4, r = s & 15;
    int k = kt * 32 + (r & 3) + 8 * (r >> 2) + 4 * (lt >> 5);
    atomicAdd(&wx[((size_t)b * K_ + k) * C_ + c0 + (lt & 31)], v[i]);
  }
}

// ---------------------------------------------------------------- kernel 4
// nodes = (wx - wsum*anchor)/sigma/(wsum+eps); intra L2-norm -> out0; gsum.
__global__ void k_nodes(const float* __restrict__ wx,
                        const float* __restrict__ wsum,
                        const float* __restrict__ anchor,
                        const float* __restrict__ invsig,
                        float* __restrict__ out0,
                        float* __restrict__ gsum) {
  const int k = blockIdx.x, b = blockIdx.y;
  const int tid = threadIdx.x;
  float wsv = wsum[b * K_ + k];
  float winv = 1.f / (wsv + 1e-9f);
  float vals[4];
  float local = 0.f;
#pragma unroll
  for (int r = 0; r < 4; r++) {
    int c = r * 128 + tid;
    float w = wx[((size_t)b * K_ + k) * C_ + c];
    float v = (w - wsv * anchor[k * C_ + c]) * invsig[k * C_ + c] * winv;
    vals[r] = v;
    local = fmaf(v, v, local);
  }
  float v = local;
#pragma unroll
  for (int off = 32; off; off >>= 1) v += __shfl_down(v, off);
  __shared__ float red[2];
  if ((tid & 63) == 0) red[tid >> 6] = v;
  __syncthreads();
  float sumsq = red[0] + red[1];
  float norm = sqrtf(sumsq);
  float scale = 1.f / fmaxf(norm, 1e-12f);
#pragma unroll
  for (int r = 0; r < 4; r++) {
    int c = r * 128 + tid;
    out0[((size_t)b * K_ + k) * C_ + c] = vals[r] * scale;
  }
  if (tid == 0) atomicAdd(&gsum[b], sumsq * scale * scale);
}

// ---------------------------------------------------------------- kernel 5
// Global L2 scale in place on out0 ([B][K*C] flat == reference (B,C,K)).
__global__ void k_final(float* __restrict__ out0,
                        const float* __restrict__ gsum) {
  for (int i = blockIdx.x * 256 + threadIdx.x; i < B_ * K_ * C_;
       i += gridDim.x * 256) {
    int b = i >> 15;  // K_*C_ = 32768
    out0[i] = out0[i] * (1.f / fmaxf(sqrtf(gsum[b]), 1e-12f));
  }
}

// ---------------------------------------------------------------- launch
extern "C" void kernel_launch(void* const* d_in, const int* in_sizes, int n_in,
                              void* d_out, int out_size, void* d_ws, size_t ws_size,
                              hipStream_t stream) {
  const float* x = (const float*)d_in[0];       // [B,C,H,W]
  const float* anchor = (const float*)d_in[1];  // [K,C]
  const float* sraw = (const float*)d_in[2];    // [K,C]
  float* out0 = (float*)d_out;                          // [B,C,K] flat
  float* soft = out0 + (size_t)B_ * C_ * K_;            // [B,K,N] (output 1)
  float* ws = (float*)d_ws;

  unsigned* pbig = (unsigned*)(ws + OFF_PBIG);
  float* invsig = ws + OFF_INVSIG;
  float* wsum = ws + OFF_WSUM;
  float* gsum = ws + OFF_GSUM;
  float* wx = ws + OFF_WX;

  k_prep<<<K_, 256, 0, stream>>>(anchor, sraw, pbig, invsig, wsum, gsum, wx);
  k_dist<<<1024, 256, 0, stream>>>(x, pbig, soft, wsum);
  k_agg<<<1024, 256, 0, stream>>>(x, soft, wx);
  k_nodes<<<dim3(K_, B_), 128, 0, stream>>>(wx, wsum, anchor, invsig, out0,
                                            gsum);
  k_final<<<512, 256, 0, stream>>>(out0, gsum);
}

// Round 8
// 291.935 us; speedup vs baseline: 1.4389x; 1.1255x over previous
//
#include <hip/hip_runtime.h>
#include <math.h>

// Problem constants (fixed by reference setup_inputs)
#define B_ 16
#define C_ 512
#define N_ 4096   // 64*64
#define K_ 64

// Workspace layout (float offsets). Total ~689K floats = 2.76 MB.
#define OFF_PBIG    0         // [16 chunk][16 kstep][2 kh][64 lane] uint4 = 512 KB
#define OFF_INVSIG  131072    // [K][C] 1/sigma fp32
#define OFF_WSUM    163840    // [B][K]
#define OFF_GSUM    164864    // [B]
#define OFF_WX      164992    // [B][K][C] fp32, atomic-accumulated by k_agg

typedef short bf16x8 __attribute__((ext_vector_type(8)));   // 8 bf16 in 4 VGPRs
typedef float f32x16 __attribute__((ext_vector_type(16)));  // MFMA 32x32 accumulator

union U4 { uint4 u; bf16x8 b; };

__device__ __forceinline__ unsigned hi16(float f) { return __float_as_uint(f) >> 16; }
__device__ __forceinline__ unsigned hi16rne(float f) {
  return (__float_as_uint(f) + 0x8000u) >> 16;
}
__device__ __forceinline__ float fromhi(unsigned h) { return __uint_as_float(h << 16); }
// pack two floats' truncated-bf16 into one dword: low16 = bf16(lo), high16 = bf16(hi)
__device__ __forceinline__ unsigned pk(float lo, float hi) {
  return (__float_as_uint(lo) >> 16) | (__float_as_uint(hi) & 0xFFFF0000u);
}

// ---------------------------------------------------------------- kernel 1
// Build pbig (MFMA-fragment order), invsig; zero wsum/gsum/wx. One block per k.
// pbig uint4 index for (k,c): chunk=c>>5, ks=(c&31)>>1, lh=c&1, kh=k>>5:
//   (((chunk*16+ks)*2+kh)*64 + lh*32 + (k&31))
// so a wave's A-fragment load in k_dist is one coalesced uint4 per lane.
__global__ void k_prep(const float* __restrict__ anchor,
                       const float* __restrict__ sraw,
                       unsigned* __restrict__ pbig,
                       float* __restrict__ invsig,
                       float* __restrict__ wsum,
                       float* __restrict__ gsum,
                       float* __restrict__ wx) {
  const int k = blockIdx.x;
  const int t = threadIdx.x;
  __shared__ float s_is2[C_], s_m[C_];
  __shared__ float red[4];
  float part = 0.f;
#pragma unroll
  for (int r = 0; r < 2; r++) {
    int c = r * 256 + t;
    float a = anchor[k * C_ + c];
    float sg = 1.f / (1.f + __expf(-sraw[k * C_ + c]));
    float is = 1.f / sg;
    float is2 = is * is;
    s_is2[c] = is2;
    s_m[c] = -2.f * a * is2;
    invsig[k * C_ + c] = is;
    part = fmaf(a * a, is2, part);
  }
  float v = part;
#pragma unroll
  for (int off = 32; off; off >>= 1) v += __shfl_down(v, off);
  if ((t & 63) == 0) red[t >> 6] = v;
  __syncthreads();
  float cst = red[0] + red[1] + red[2] + red[3];
  unsigned ch = hi16(cst);
  unsigned clr = hi16rne(cst - fromhi(ch));
#pragma unroll
  for (int r = 0; r < 2; r++) {
    int c = r * 256 + t;
    float is2 = s_is2[c], m = s_m[c];
    unsigned ih = hi16(is2);
    unsigned ilr = hi16rne(is2 - fromhi(ih));
    unsigned mh = hi16(m);
    unsigned mlr = hi16rne(m - fromhi(mh));
    int chunk = c >> 5, ks = (c & 31) >> 1, lh = c & 1;
    int kh = k >> 5;
    size_t dst = ((((size_t)chunk * 16 + ks) * 2 + kh) * 64 + lh * 32 + (k & 31)) * 4;
    pbig[dst + 0] = ih | (ilr << 16);
    pbig[dst + 1] = ih | (mh << 16);
    pbig[dst + 2] = mlr | (mh << 16);
    pbig[dst + 3] = (c == 0) ? (ch | (clr << 16)) : 0u;
  }
  // zero wx slice for this k-block: 8192 floats = 2048 float4
  float4 z4 = make_float4(0.f, 0.f, 0.f, 0.f);
  float4* wz = (float4*)(wx + (size_t)k * 8192);
#pragma unroll
  for (int it = 0; it < 8; it++) wz[it * 256 + t] = z4;
  if (k == 0) {
    for (int i = t; i < B_ * K_; i += 256) wsum[i] = 0.f;
    if (t < B_) gsum[t] = 0.f;
  }
}

// ---------------------------------------------------------------- kernel 2
// MFMA distance GEMM (split-bf16, inner dim 4096) + softmax.
// v6: explicit register pipeline. Wave tile 32k x 64n: each A-fragment feeds
// TWO MFMA chains (accA/accB -> halves L2 A-traffic, doubles per-wave ILP).
// A-frags AND x double-buffered in named register arrays (all-static
// indices) so 48 loads are in flight while the current chunk computes.
// (v5's 56-VGPR compile kept ~0 A-loads in flight -> latency-bound at 118us.)
// Grid 512 (XCD-swizzled), 4 waves/block, launch_bounds(256,2) -> 256 VGPR cap.
__global__ __launch_bounds__(256, 2) void k_dist(
    const float* __restrict__ x,
    const unsigned* __restrict__ pbig,
    float* __restrict__ soft,
    float* __restrict__ wsum) {
  const int bid = blockIdx.x;
  const int swz = (bid & 7) * 64 + (bid >> 3);   // XCD-contiguous remap (512%8==0)
  const int b = swz >> 5;                        // 16 batches
  const int nblk = (swz & 31) * 128;             // 32 n-blocks of 128
  const int tid = threadIdx.x;
  const int wid = tid >> 6;
  const int lane = tid & 63;
  const int l31 = lane & 31;
  const int lh = lane >> 5;
  const int kh = wid & 1;                        // this wave's k-half
  const int n0 = nblk + (wid >> 1) * 64;         // wave's 64 n-columns

  __shared__ float cmax[4][2][32];
  __shared__ float csum[4][2][32];

  f32x16 accA, accB;
#pragma unroll
  for (int i = 0; i < 16; i++) { accA[i] = 0.f; accB[i] = 0.f; }

  const float* xcol0 = x + (size_t)b * (C_ * N_) + n0 + l31;
  const float* xcol1 = xcol0 + 32;
  const uint4* pf = (const uint4*)pbig + (size_t)kh * 64 + lane;

#define PACKMF(XV, CC, ACC, AFRAG)                                            \
  {                                                                           \
    float xv = (XV);                                                          \
    float x2 = xv * xv;                                                       \
    unsigned u = __float_as_uint(xv);                                         \
    unsigned u2 = __float_as_uint(x2);                                        \
    unsigned uhf = u & 0xFFFF0000u;                                           \
    unsigned u2hf = u2 & 0xFFFF0000u;                                         \
    float xl = xv - __uint_as_float(uhf);                                     \
    float x2l = x2 - __uint_as_float(u2hf);                                   \
    U4 bf;                                                                    \
    bf.u.x = (u2 >> 16) | u2hf;                                               \
    bf.u.y = ((__float_as_uint(x2l) + 0x8000u) >> 16) | uhf;                  \
    bf.u.z = (u >> 16) | ((__float_as_uint(xl) + 0x8000u) & 0xFFFF0000u);     \
    bf.u.w = ((CC) == 0) ? 0x3F803F80u : 0u;                                  \
    ACC = __builtin_amdgcn_mfma_f32_32x32x16_bf16((AFRAG), bf.b, ACC, 0, 0, 0); \
  }

// One chunk: optionally prefetch chunk+1 into FNXT/XN*, then 16 ksteps
// consuming FCUR/XC* (each A-frag feeds both acc chains).
#define CHUNK_BODY(CHUNK, FCUR, FNXT, XC0, XC1, XN0, XN1, PREFETCH)           \
  {                                                                           \
    const int chunk_ = (CHUNK);                                               \
    if (PREFETCH) {                                                           \
      _Pragma("unroll")                                                       \
      for (int kk = 0; kk < 16; kk++) {                                       \
        FNXT[kk].u = pf[(size_t)((chunk_ + 1) * 16 + kk) * 128];              \
        XN0[kk] = xcol0[(size_t)((chunk_ + 1) * 32 + kk * 2 + lh) * N_];      \
        XN1[kk] = xcol1[(size_t)((chunk_ + 1) * 32 + kk * 2 + lh) * N_];      \
      }                                                                       \
    }                                                                         \
    _Pragma("unroll")                                                         \
    for (int ks = 0; ks < 16; ks++) {                                         \
      const int c = chunk_ * 32 + ks * 2 + lh;                                \
      PACKMF(XC0[ks], c, accA, FCUR[ks].b);                                   \
      PACKMF(XC1[ks], c, accB, FCUR[ks].b);                                   \
    }                                                                         \
  }

  U4 f0_[16], f1_[16];
  float a0_[16], a1_[16], b0_[16], b1_[16];
#pragma unroll
  for (int kk = 0; kk < 16; kk++) {
    f0_[kk].u = pf[(size_t)kk * 128];
    a0_[kk] = xcol0[(size_t)(kk * 2 + lh) * N_];
    a1_[kk] = xcol1[(size_t)(kk * 2 + lh) * N_];
  }
  for (int c2 = 0; c2 < 8; c2++) {
    CHUNK_BODY(2 * c2,     f0_, f1_, a0_, a1_, b0_, b1_, 1);
    CHUNK_BODY(2 * c2 + 1, f1_, f0_, b0_, b1_, a0_, a1_, (c2 < 7));
  }
#undef CHUNK_BODY
#undef PACKMF

  // ---- softmax over k=64: in-wave (rows via lane^32) then cross-wave
  // (k-half partner wid^1) via tiny LDS max/sum arrays. Two n-columns. ----
  float* softb = soft + (size_t)b * (K_ * N_);
  float mA = -3.4e38f, mB = -3.4e38f;
#pragma unroll
  for (int r = 0; r < 16; r++) {
    accA[r] *= -0.5f; mA = fmaxf(mA, accA[r]);
    accB[r] *= -0.5f; mB = fmaxf(mB, accB[r]);
  }
  mA = fmaxf(mA, __shfl_xor(mA, 32));
  mB = fmaxf(mB, __shfl_xor(mB, 32));
  cmax[wid][0][l31] = mA;
  cmax[wid][1][l31] = mB;
  __syncthreads();
  mA = fmaxf(cmax[wid][0][l31], cmax[wid ^ 1][0][l31]);
  mB = fmaxf(cmax[wid][1][l31], cmax[wid ^ 1][1][l31]);
  float sA = 0.f, sB = 0.f;
#pragma unroll
  for (int r = 0; r < 16; r++) {
    accA[r] = __expf(accA[r] - mA); sA += accA[r];
    accB[r] = __expf(accB[r] - mB); sB += accB[r];
  }
  sA += __shfl_xor(sA, 32);
  sB += __shfl_xor(sB, 32);
  csum[wid][0][l31] = sA;
  csum[wid][1][l31] = sB;
  __syncthreads();
  float invA = 1.f / (csum[wid][0][l31] + csum[wid ^ 1][0][l31]);
  float invB = 1.f / (csum[wid][1][l31] + csum[wid ^ 1][1][l31]);
  const int nc0 = n0 + l31;
#pragma unroll
  for (int r = 0; r < 16; r++) {
    int k0 = kh * 32 + (r & 3) + 8 * (r >> 2) + 4 * lh;
    float wA = accA[r] * invA; accA[r] = wA;
    softb[(size_t)k0 * N_ + nc0] = wA;
    float wB = accB[r] * invB; accB[r] = wB;
    softb[(size_t)k0 * N_ + nc0 + 32] = wB;
  }
  // ---- wsum: both columns belong to b; reduce over 32 lanes, one atomic ----
#pragma unroll
  for (int r = 0; r < 16; r++) {
    float v = accA[r] + accB[r];
    v += __shfl_xor(v, 1);
    v += __shfl_xor(v, 2);
    v += __shfl_xor(v, 4);
    v += __shfl_xor(v, 8);
    v += __shfl_xor(v, 16);
    if (l31 == 0) {
      int k0 = kh * 32 + (r & 3) + 8 * (r >> 2) + 4 * lh;
      atomicAdd(&wsum[b * K_ + k0], v);
    }
  }
}

// ---------------------------------------------------------------- kernel 3
// Aggregation GEMM via MFMA: wx[b,k,c] += sum_n soft[b,k,n]*x[b,c,n].
// n split 4 ways (z), grid 1024 1D with XCD-group swizzle. Partials
// atomicAdd'ed into zero-initialized wx. v6: unroll 2 for deeper load batching.
__global__ __launch_bounds__(256, 4) void k_agg(const float* __restrict__ x,
                                                const float* __restrict__ soft,
                                                float* __restrict__ wx) {
  const int bid = blockIdx.x;
  const int xcd = bid & 7, slot = bid >> 3;      // 128 slots per XCD
  const int grp = (slot >> 4) * 8 + xcd;         // 0..63 = (b,z) group
  const int ct = slot & 15;
  const int b = grp & 15, z = grp >> 4;
  const int tid = threadIdx.x;
  const int wid = tid >> 6, lane = tid & 63, l31 = lane & 31, lh = lane >> 5;
  const int c0 = ct * 32;
  const int n0 = z * 1024 + wid * 256;
  __shared__ float red[4][64][36];  // stride 36 floats (odd x16B) per lane

  f32x16 acc[2];
#pragma unroll
  for (int kt = 0; kt < 2; kt++)
#pragma unroll
    for (int i = 0; i < 16; i++) acc[kt][i] = 0.f;

  const float* sb = soft + (size_t)b * (K_ * N_);
  const float* xr = x + (size_t)b * (C_ * N_) + (size_t)(c0 + l31) * N_;
  const float* s0 = sb + (size_t)l31 * N_;
  const float* s1 = sb + (size_t)(32 + l31) * N_;

#pragma unroll 2
  for (int kstep = 0; kstep < 16; kstep++) {
    int nb = n0 + kstep * 16 + lh * 8;
    float4 f0 = *(const float4*)&s0[nb];
    float4 f1 = *(const float4*)&s0[nb + 4];
    float4 g0 = *(const float4*)&s1[nb];
    float4 g1 = *(const float4*)&s1[nb + 4];
    float4 h0 = *(const float4*)&xr[nb];
    float4 h1 = *(const float4*)&xr[nb + 4];
    U4 A0, A1, Bf;
    A0.u.x = pk(f0.x, f0.y); A0.u.y = pk(f0.z, f0.w);
    A0.u.z = pk(f1.x, f1.y); A0.u.w = pk(f1.z, f1.w);
    A1.u.x = pk(g0.x, g0.y); A1.u.y = pk(g0.z, g0.w);
    A1.u.z = pk(g1.x, g1.y); A1.u.w = pk(g1.z, g1.w);
    Bf.u.x = pk(h0.x, h0.y); Bf.u.y = pk(h0.z, h0.w);
    Bf.u.z = pk(h1.x, h1.y); Bf.u.w = pk(h1.z, h1.w);
    acc[0] = __builtin_amdgcn_mfma_f32_32x32x16_bf16(A0.b, Bf.b, acc[0], 0, 0, 0);
    acc[1] = __builtin_amdgcn_mfma_f32_32x32x16_bf16(A1.b, Bf.b, acc[1], 0, 0, 0);
  }
  // stash per-wave partials
#pragma unroll
  for (int kt = 0; kt < 2; kt++)
#pragma unroll
    for (int q = 0; q < 4; q++) {
      float4 vv = make_float4(acc[kt][q * 4], acc[kt][q * 4 + 1],
                              acc[kt][q * 4 + 2], acc[kt][q * 4 + 3]);
      *(float4*)&red[wid][lane][kt * 16 + q * 4] = vv;
    }
  __syncthreads();
  // cross-wave reduce + atomic accumulate (2048 outputs, 8 per thread)
  const int lt = tid & 63, sb4 = (tid >> 6) * 8;
  float v[8];
#pragma unroll
  for (int i = 0; i < 8; i++) v[i] = 0.f;
#pragma unroll
  for (int w = 0; w < 4; w++)
#pragma unroll
    for (int i = 0; i < 8; i++) v[i] += red[w][lt][sb4 + i];
#pragma unroll
  for (int i = 0; i < 8; i++) {
    int s = sb4 + i;
    int kt = s >> 4, r = s & 15;
    int k = kt * 32 + (r & 3) + 8 * (r >> 2) + 4 * (lt >> 5);
    atomicAdd(&wx[((size_t)b * K_ + k) * C_ + c0 + (lt & 31)], v[i]);
  }
}

// ---------------------------------------------------------------- kernel 4
// nodes = (wx - wsum*anchor)/sigma/(wsum+eps); intra L2-norm -> out0; gsum.
__global__ void k_nodes(const float* __restrict__ wx,
                        const float* __restrict__ wsum,
                        const float* __restrict__ anchor,
                        const float* __restrict__ invsig,
                        float* __restrict__ out0,
                        float* __restrict__ gsum) {
  const int k = blockIdx.x, b = blockIdx.y;
  const int tid = threadIdx.x;
  float wsv = wsum[b * K_ + k];
  float winv = 1.f / (wsv + 1e-9f);
  float vals[4];
  float local = 0.f;
#pragma unroll
  for (int r = 0; r < 4; r++) {
    int c = r * 128 + tid;
    float w = wx[((size_t)b * K_ + k) * C_ + c];
    float v = (w - wsv * anchor[k * C_ + c]) * invsig[k * C_ + c] * winv;
    vals[r] = v;
    local = fmaf(v, v, local);
  }
  float v = local;
#pragma unroll
  for (int off = 32; off; off >>= 1) v += __shfl_down(v, off);
  __shared__ float red[2];
  if ((tid & 63) == 0) red[tid >> 6] = v;
  __syncthreads();
  float sumsq = red[0] + red[1];
  float norm = sqrtf(sumsq);
  float scale = 1.f / fmaxf(norm, 1e-12f);
#pragma unroll
  for (int r = 0; r < 4; r++) {
    int c = r * 128 + tid;
    out0[((size_t)b * K_ + k) * C_ + c] = vals[r] * scale;
  }
  if (tid == 0) atomicAdd(&gsum[b], sumsq * scale * scale);
}

// ---------------------------------------------------------------- kernel 5
// Global L2 scale in place on out0 ([B][K*C] flat == reference (B,C,K)).
__global__ void k_final(float* __restrict__ out0,
                        const float* __restrict__ gsum) {
  for (int i = blockIdx.x * 256 + threadIdx.x; i < B_ * K_ * C_;
       i += gridDim.x * 256) {
    int b = i >> 15;  // K_*C_ = 32768
    out0[i] = out0[i] * (1.f / fmaxf(sqrtf(gsum[b]), 1e-12f));
  }
}

// ---------------------------------------------------------------- launch
extern "C" void kernel_launch(void* const* d_in, const int* in_sizes, int n_in,
                              void* d_out, int out_size, void* d_ws, size_t ws_size,
                              hipStream_t stream) {
  const float* x = (const float*)d_in[0];       // [B,C,H,W]
  const float* anchor = (const float*)d_in[1];  // [K,C]
  const float* sraw = (const float*)d_in[2];    // [K,C]
  float* out0 = (float*)d_out;                          // [B,C,K] flat
  float* soft = out0 + (size_t)B_ * C_ * K_;            // [B,K,N] (output 1)
  float* ws = (float*)d_ws;

  unsigned* pbig = (unsigned*)(ws + OFF_PBIG);
  float* invsig = ws + OFF_INVSIG;
  float* wsum = ws + OFF_WSUM;
  float* gsum = ws + OFF_GSUM;
  float* wx = ws + OFF_WX;

  k_prep<<<K_, 256, 0, stream>>>(anchor, sraw, pbig, invsig, wsum, gsum, wx);
  k_dist<<<512, 256, 0, stream>>>(x, pbig, soft, wsum);
  k_agg<<<1024, 256, 0, stream>>>(x, soft, wx);
  k_nodes<<<dim3(K_, B_), 128, 0, stream>>>(wx, wsum, anchor, invsig, out0,
                                            gsum);
  k_final<<<512, 256, 0, stream>>>(out0, gsum);
}